// Round 1
// baseline (866.792 us; speedup 1.0000x reference)
//
#include <hip/hip_runtime.h>
#include <math.h>

// Problem constants (from reference)
#define Bz   8
#define Lz   8192
#define Hz   1024
#define Nz   64
#define BLz  (Bz * Lz)   // 65536

// ---------------------------------------------------------------------------
// GEMM1: u[bl, n] = sum_h input[bl, h] * Win[h, n]
// block = 256 threads, 32 rows per block, K staged in LDS chunks of 128.
// Each thread: 8 rows x 1 col accumulators; LDS reads are wave-broadcast.
// ---------------------------------------------------------------------------
__global__ __launch_bounds__(256) void gemm_in_kernel(
    const float* __restrict__ inp, const float* __restrict__ Win,
    float* __restrict__ u)
{
    __shared__ float sA[128][33];   // [k][row], pad 33 to limit store conflicts
    const int rowBase = blockIdx.x * 32;
    const int t  = threadIdx.x;
    const int n  = t & 63;          // output state column
    const int r0 = (t >> 6) * 8;    // 8 rows per thread

    float acc[8];
#pragma unroll
    for (int j = 0; j < 8; ++j) acc[j] = 0.f;

    for (int kc = 0; kc < Hz; kc += 128) {
        // stage 32 rows x 128 k (coalesced float4)
#pragma unroll
        for (int j = 0; j < 4; ++j) {
            int f  = t + 256 * j;        // 0..1023 float4 slots
            int r  = f >> 5;             // 0..31
            int k4 = (f & 31) * 4;       // 0..124
            const float4 v = *reinterpret_cast<const float4*>(
                inp + (size_t)(rowBase + r) * Hz + kc + k4);
            sA[k4 + 0][r] = v.x;
            sA[k4 + 1][r] = v.y;
            sA[k4 + 2][r] = v.z;
            sA[k4 + 3][r] = v.w;
        }
        __syncthreads();

#pragma unroll 4
        for (int k = 0; k < 128; ++k) {
            float wv = Win[(size_t)(kc + k) * Nz + n];   // lanes n=0..63 coalesced, L2-hot
#pragma unroll
            for (int j = 0; j < 8; ++j)
                acc[j] = fmaf(sA[k][r0 + j], wv, acc[j]); // broadcast LDS read
        }
        __syncthreads();
    }

#pragma unroll
    for (int j = 0; j < 8; ++j)
        u[(size_t)(rowBase + r0 + j) * Nz + n] = acc[j];
}

// ---------------------------------------------------------------------------
// Scan: x[t] = a*x[t-1] + u[t] (complex a, real u), chunked with warm-up.
// |a| = e^{-0.5} => 192 warm-up steps give truncation error ~e^{-96}.
// grid = (B, L/CHUNK), block = 64 (one lane per state n).
// ---------------------------------------------------------------------------
#define CHUNK 512
#define WARM  192

__global__ __launch_bounds__(64) void scan_kernel(
    const float* __restrict__ u, const float* __restrict__ init,
    const float* __restrict__ freq, const float* __restrict__ dec,
    float* __restrict__ convr, float* __restrict__ fs, int fs_mode)
{
    const int n = threadIdx.x;   // state index
    const int b = blockIdx.x;    // batch
    const int c = blockIdx.y;    // time chunk

    const float mag = expf(-expf(dec[n]));
    const float fr  = freq[n];
    const float ar  = mag * cosf(fr);
    const float ai  = mag * sinf(fr);

    const float* ub = u + (size_t)b * Lz * Nz + n;
    float* cb = convr + (size_t)b * Lz * Nz + n;

    float xr, xi;
    const int t0 = c * CHUNK + 1;

    if (c == 0) {
        xr = init[b * Nz + n];
        xi = 0.f;
    } else {
        xr = 0.f; xi = 0.f;
        for (int tt = t0 - WARM; tt < t0; ++tt) {
            float uv = ub[(size_t)(tt - 1) * Nz];
            float nr = fmaf(ar, xr, fmaf(-ai, xi, uv));
            float ni = fmaf(ar, xi, ai * xr);
            xr = nr; xi = ni;
        }
    }

    for (int tt = t0; tt < t0 + CHUNK; ++tt) {
        float uv = ub[(size_t)(tt - 1) * Nz];
        float nr = fmaf(ar, xr, fmaf(-ai, xi, uv));
        float ni = fmaf(ar, xi, ai * xr);
        xr = nr; xi = ni;
        cb[(size_t)(tt - 1) * Nz] = xr;   // lanes n coalesced
    }

    // last chunk holds x[L] = final_state
    if (t0 + CHUNK - 1 == Lz && fs_mode) {
        if (fs_mode == 2) {            // complex64 interleaved re,im
            fs[(b * Nz + n) * 2 + 0] = xr;
            fs[(b * Nz + n) * 2 + 1] = xi;
        } else {                       // real only
            fs[b * Nz + n] = xr;
        }
    }
}

// ---------------------------------------------------------------------------
// GEMM2: out[bl, h] = sum_n conv[bl, n] * Wout[n, h]
// block = 256 threads: 32 rows x 128 cols per block; Wout tile + conv tile in LDS.
// Each thread: 4 rows x 4 cols register tile.
// ---------------------------------------------------------------------------
__global__ __launch_bounds__(256) void gemm_out_kernel(
    const float* __restrict__ convr, const float* __restrict__ Wout,
    float* __restrict__ out)
{
    __shared__ float sW[64][128];   // 32 KB
    __shared__ float sC[32][65];    // 8.3 KB, padded

    const int cc      = blockIdx.x * 128;
    const int rowBase = blockIdx.y * 32;
    const int t = threadIdx.x;

    // stage Wout tile (64 x 128), coalesced float4
#pragma unroll
    for (int j = 0; j < 8; ++j) {
        int f  = t + 256 * j;        // 0..2047 float4 slots
        int nr = f >> 5;             // 0..63
        int c4 = (f & 31) * 4;       // 0..124
        *reinterpret_cast<float4*>(&sW[nr][c4]) =
            *reinterpret_cast<const float4*>(Wout + (size_t)nr * Hz + cc + c4);
    }
    // stage conv tile (32 x 64)
#pragma unroll
    for (int j = 0; j < 2; ++j) {
        int f  = t + 256 * j;        // 0..511 float4 slots
        int r  = f >> 4;             // 0..31
        int n4 = (f & 15) * 4;       // 0..60
        float4 v = *reinterpret_cast<const float4*>(
            convr + (size_t)(rowBase + r) * Nz + n4);
        sC[r][n4 + 0] = v.x;
        sC[r][n4 + 1] = v.y;
        sC[r][n4 + 2] = v.z;
        sC[r][n4 + 3] = v.w;
    }
    __syncthreads();

    const int cl = (t & 31) * 4;     // col offset within tile (0..124)
    const int r0 = (t >> 5) * 4;     // row offset (0..28)

    float acc[4][4];
#pragma unroll
    for (int j = 0; j < 4; ++j)
#pragma unroll
        for (int q = 0; q < 4; ++q) acc[j][q] = 0.f;

#pragma unroll 8
    for (int nn = 0; nn < 64; ++nn) {
        float4 w = *reinterpret_cast<const float4*>(&sW[nn][cl]);
#pragma unroll
        for (int j = 0; j < 4; ++j) {
            float cv = sC[r0 + j][nn];   // half-wave broadcast (2-way, free)
            acc[j][0] = fmaf(cv, w.x, acc[j][0]);
            acc[j][1] = fmaf(cv, w.y, acc[j][1]);
            acc[j][2] = fmaf(cv, w.z, acc[j][2]);
            acc[j][3] = fmaf(cv, w.w, acc[j][3]);
        }
    }

#pragma unroll
    for (int j = 0; j < 4; ++j) {
        float4 v = make_float4(acc[j][0], acc[j][1], acc[j][2], acc[j][3]);
        *reinterpret_cast<float4*>(
            out + (size_t)(rowBase + r0 + j) * Hz + cc + cl) = v;
    }
}

// ---------------------------------------------------------------------------
extern "C" void kernel_launch(void* const* d_in, const int* in_sizes, int n_in,
                              void* d_out, int out_size, void* d_ws, size_t ws_size,
                              hipStream_t stream)
{
    const float* inp  = (const float*)d_in[0];   // (B, L, H)
    const float* init = (const float*)d_in[1];   // (B, N)
    const float* Win  = (const float*)d_in[2];   // (H, N)
    const float* Wout = (const float*)d_in[3];   // (N, H)
    const float* freq = (const float*)d_in[4];   // (N,)
    const float* dec  = (const float*)d_in[5];   // (N,)
    float* out = (float*)d_out;

    float* u    = (float*)d_ws;                  // BL*N floats = 16.8 MB
    float* conv = u + (size_t)BLz * Nz;          // BL*N floats = 16.8 MB

    // final_state layout inferred from out_size (complex64 -> 2 floats/elem)
    const int extra   = out_size - BLz * Hz;
    const int fs_mode = (extra >= 2 * Bz * Nz) ? 2 : (extra >= Bz * Nz ? 1 : 0);
    float* fs = out + (size_t)BLz * Hz;

    hipLaunchKernelGGL(gemm_in_kernel, dim3(BLz / 32), dim3(256), 0, stream,
                       inp, Win, u);
    hipLaunchKernelGGL(scan_kernel, dim3(Bz, Lz / CHUNK), dim3(64), 0, stream,
                       u, init, freq, dec, conv, fs, fs_mode);
    hipLaunchKernelGGL(gemm_out_kernel, dim3(Hz / 128, BLz / 32), dim3(256), 0, stream,
                       conv, Wout, out);
}

// Round 2
// 661.984 us; speedup vs baseline: 1.3094x; 1.3094x over previous
//
#include <hip/hip_runtime.h>
#include <math.h>

#define Bz   8
#define Lz   8192
#define Hz   1024
#define Nz   64
#define BLz  (Bz * Lz)   // 65536

typedef __attribute__((ext_vector_type(8))) short bf16x8;
typedef __attribute__((ext_vector_type(4))) float f32x4;

__device__ inline unsigned int bfpack2(float a, float b) {
    // round-to-nearest-ish (round half up) bf16 pack of two floats
    unsigned int ua = __float_as_uint(a) + 0x8000u;
    unsigned int ub = __float_as_uint(b) + 0x8000u;
    return (ua >> 16) | (ub & 0xFFFF0000u);
}
__device__ inline unsigned short bf1(float a) {
    return (unsigned short)((__float_as_uint(a) + 0x8000u) >> 16);
}

// ---------------------------------------------------------------------------
// Prep: WinT[n][k] = bf16(Win[k][n])  (64 x 1024)
//       WoutT[h][n] = bf16(Wout[n][h]) (1024 x 64)
// ---------------------------------------------------------------------------
__global__ __launch_bounds__(256) void prep_kernel(
    const float* __restrict__ Win, const float* __restrict__ Wout,
    unsigned short* __restrict__ WinT, unsigned short* __restrict__ WoutT)
{
    int i = blockIdx.x * 256 + threadIdx.x;   // 0 .. 131071
    if (i < 65536) {
        int n = i >> 10, k = i & 1023;
        WinT[i] = bf1(Win[k * Nz + n]);
    } else {
        int j = i - 65536;
        int h = j >> 6, n = j & 63;
        WoutT[j] = bf1(Wout[n * Hz + h]);
    }
}

// ---------------------------------------------------------------------------
// GEMM1: u[bl,n] = sum_h input[bl,h] * Win[h,n]   (M=65536, N=64, K=1024)
// block 256 (4 waves). M-tile 128 (wave: 2 m-subtiles of 16), N=64 (4 n-tiles),
// K-chunk 64. mfma_f32_16x16x32_bf16.
// ---------------------------------------------------------------------------
__global__ __launch_bounds__(256) void gemm_in_kernel(
    const float* __restrict__ inp, const unsigned short* __restrict__ WinT,
    float* __restrict__ u)
{
    __shared__ unsigned short sA[128][72];  // pad 72: 2-way bank alias only
    __shared__ unsigned short sB[64][72];

    const int t    = threadIdx.x;
    const int wid  = t >> 6;
    const int lane = t & 63;
    const int nl   = lane & 15;      // row-in-tile for A/B frags, col for C
    const int q    = lane >> 4;      // quad
    const size_t rowBase = (size_t)blockIdx.x * 128;

    f32x4 acc[2][4];
#pragma unroll
    for (int m = 0; m < 2; ++m)
#pragma unroll
        for (int nt = 0; nt < 4; ++nt) acc[m][nt] = (f32x4){0.f, 0.f, 0.f, 0.f};

    for (int kc = 0; kc < Hz; kc += 64) {
        __syncthreads();
        // stage A: 128 rows x 64 k fp32 -> bf16 LDS
#pragma unroll
        for (int j = 0; j < 4; ++j) {
            int f = j * 256 + t;           // chunk of 8 floats
            int r = f >> 3, c = f & 7;
            const float* p = inp + (rowBase + r) * Hz + kc + c * 8;
            float4 v0 = *reinterpret_cast<const float4*>(p);
            float4 v1 = *reinterpret_cast<const float4*>(p + 4);
            uint4 d;
            d.x = bfpack2(v0.x, v0.y);
            d.y = bfpack2(v0.z, v0.w);
            d.z = bfpack2(v1.x, v1.y);
            d.w = bfpack2(v1.z, v1.w);
            *reinterpret_cast<uint4*>(&sA[r][c * 8]) = d;
        }
        // stage B^T: 64 n-rows x 64 k bf16 from WinT
#pragma unroll
        for (int j = 0; j < 2; ++j) {
            int f = j * 256 + t;
            int r = f >> 3, c = f & 7;
            uint4 w = *reinterpret_cast<const uint4*>(WinT + (size_t)r * Hz + kc + c * 8);
            *reinterpret_cast<uint4*>(&sB[r][c * 8]) = w;
        }
        __syncthreads();

#pragma unroll
        for (int ks = 0; ks < 2; ++ks) {
            bf16x8 a0 = *reinterpret_cast<bf16x8*>(&sA[wid * 32 + nl][ks * 32 + q * 8]);
            bf16x8 a1 = *reinterpret_cast<bf16x8*>(&sA[wid * 32 + 16 + nl][ks * 32 + q * 8]);
#pragma unroll
            for (int nt = 0; nt < 4; ++nt) {
                bf16x8 b = *reinterpret_cast<bf16x8*>(&sB[nt * 16 + nl][ks * 32 + q * 8]);
                acc[0][nt] = __builtin_amdgcn_mfma_f32_16x16x32_bf16(a0, b, acc[0][nt], 0, 0, 0);
                acc[1][nt] = __builtin_amdgcn_mfma_f32_16x16x32_bf16(a1, b, acc[1][nt], 0, 0, 0);
            }
        }
    }

    // epilogue: C/D layout col = lane&15, row = quad*4 + reg
#pragma unroll
    for (int m = 0; m < 2; ++m)
#pragma unroll
        for (int nt = 0; nt < 4; ++nt)
#pragma unroll
            for (int reg = 0; reg < 4; ++reg)
                u[(rowBase + wid * 32 + m * 16 + q * 4 + reg) * Nz + nt * 16 + nl] =
                    acc[m][nt][reg];
}

// ---------------------------------------------------------------------------
// Scan: x[t] = a*x[t-1] + u[t] (complex a). conv written as bf16.
// ---------------------------------------------------------------------------
#define CHUNK 512
#define WARM  192

__global__ __launch_bounds__(64) void scan_kernel(
    const float* __restrict__ u, const float* __restrict__ init,
    const float* __restrict__ freq, const float* __restrict__ dec,
    unsigned short* __restrict__ convb, float* __restrict__ fs, int fs_mode)
{
    const int n = threadIdx.x;
    const int b = blockIdx.x;
    const int c = blockIdx.y;

    const float mag = expf(-expf(dec[n]));
    const float fr  = freq[n];
    const float ar  = mag * cosf(fr);
    const float ai  = mag * sinf(fr);

    const float* ub = u + (size_t)b * Lz * Nz + n;
    unsigned short* cb = convb + (size_t)b * Lz * Nz + n;

    float xr, xi;
    const int t0 = c * CHUNK + 1;

    if (c == 0) {
        xr = init[b * Nz + n];
        xi = 0.f;
    } else {
        xr = 0.f; xi = 0.f;
        for (int tt = t0 - WARM; tt < t0; ++tt) {
            float uv = ub[(size_t)(tt - 1) * Nz];
            float nr = fmaf(ar, xr, fmaf(-ai, xi, uv));
            float ni = fmaf(ar, xi, ai * xr);
            xr = nr; xi = ni;
        }
    }

    for (int tt = t0; tt < t0 + CHUNK; ++tt) {
        float uv = ub[(size_t)(tt - 1) * Nz];
        float nr = fmaf(ar, xr, fmaf(-ai, xi, uv));
        float ni = fmaf(ar, xi, ai * xr);
        xr = nr; xi = ni;
        cb[(size_t)(tt - 1) * Nz] = bf1(xr);
    }

    if (t0 + CHUNK - 1 == Lz && fs_mode) {
        if (fs_mode == 2) {
            fs[(b * Nz + n) * 2 + 0] = xr;
            fs[(b * Nz + n) * 2 + 1] = xi;
        } else {
            fs[b * Nz + n] = xr;
        }
    }
}

// ---------------------------------------------------------------------------
// GEMM2: out[bl,h] = sum_n conv[bl,n] * Wout[n,h]  (M=65536, N=1024, K=64)
// block 512 (8 waves): rows = 128 (wave: 16 rows), h-slice = 256 (16 h-tiles).
// WoutT slice in LDS; A-frags direct from global (contiguous bf16 rows).
// Store each 16x16 tile immediately (acc stays tiny -> high occupancy).
// ---------------------------------------------------------------------------
__global__ __launch_bounds__(512) void gemm_out_kernel(
    const unsigned short* __restrict__ convb,
    const unsigned short* __restrict__ WoutT,
    float* __restrict__ out)
{
    __shared__ unsigned short sW[256][72];   // 36.9 KB

    const int t    = threadIdx.x;
    const int wid  = t >> 6;
    const int lane = t & 63;
    const int nl   = lane & 15;
    const int q    = lane >> 4;
    const int hBase = blockIdx.x * 256;
    const size_t rowBase = (size_t)blockIdx.y * 128 + wid * 16;

    // stage WoutT slice: 256 h-rows x 64 n
#pragma unroll
    for (int j = 0; j < 4; ++j) {
        int f = j * 512 + t;
        int r = f >> 3, c = f & 7;
        uint4 v = *reinterpret_cast<const uint4*>(WoutT + (size_t)(hBase + r) * Nz + c * 8);
        *reinterpret_cast<uint4*>(&sW[r][c * 8]) = v;
    }
    __syncthreads();

    // A fragments: conv rows (bf16, 64 per row): k = ks*32 + q*8 + j
    const unsigned short* ap = convb + (rowBase + nl) * Nz;
    bf16x8 a0 = *reinterpret_cast<const bf16x8*>(ap + q * 8);
    bf16x8 a1 = *reinterpret_cast<const bf16x8*>(ap + 32 + q * 8);

    const f32x4 zero = (f32x4){0.f, 0.f, 0.f, 0.f};
#pragma unroll
    for (int ht = 0; ht < 16; ++ht) {
        bf16x8 b0 = *reinterpret_cast<bf16x8*>(&sW[ht * 16 + nl][q * 8]);
        bf16x8 b1 = *reinterpret_cast<bf16x8*>(&sW[ht * 16 + nl][32 + q * 8]);
        f32x4 acc = __builtin_amdgcn_mfma_f32_16x16x32_bf16(a0, b0, zero, 0, 0, 0);
        acc = __builtin_amdgcn_mfma_f32_16x16x32_bf16(a1, b1, acc, 0, 0, 0);
#pragma unroll
        for (int reg = 0; reg < 4; ++reg)
            out[(rowBase + q * 4 + reg) * Hz + hBase + ht * 16 + nl] = acc[reg];
    }
}

// ---------------------------------------------------------------------------
extern "C" void kernel_launch(void* const* d_in, const int* in_sizes, int n_in,
                              void* d_out, int out_size, void* d_ws, size_t ws_size,
                              hipStream_t stream)
{
    const float* inp  = (const float*)d_in[0];   // (B, L, H)
    const float* init = (const float*)d_in[1];   // (B, N)
    const float* Win  = (const float*)d_in[2];   // (H, N)
    const float* Wout = (const float*)d_in[3];   // (N, H)
    const float* freq = (const float*)d_in[4];   // (N,)
    const float* dec  = (const float*)d_in[5];   // (N,)
    float* out = (float*)d_out;

    char* ws = (char*)d_ws;
    float*          u     = (float*)ws;                               // 16.78 MB
    unsigned short* convb = (unsigned short*)(ws + (size_t)BLz * Nz * 4);       // 8.39 MB
    unsigned short* WinT  = (unsigned short*)(ws + (size_t)BLz * Nz * 6);       // 128 KB
    unsigned short* WoutT = WinT + (size_t)Nz * Hz;                             // 128 KB

    const int extra   = out_size - BLz * Hz;
    const int fs_mode = (extra >= 2 * Bz * Nz) ? 2 : (extra >= Bz * Nz ? 1 : 0);
    float* fs = out + (size_t)BLz * Hz;

    hipLaunchKernelGGL(prep_kernel, dim3(512), dim3(256), 0, stream,
                       Win, Wout, WinT, WoutT);
    hipLaunchKernelGGL(gemm_in_kernel, dim3(BLz / 128), dim3(256), 0, stream,
                       inp, WinT, u);
    hipLaunchKernelGGL(scan_kernel, dim3(Bz, Lz / CHUNK), dim3(64), 0, stream,
                       u, init, freq, dec, convb, fs, fs_mode);
    hipLaunchKernelGGL(gemm_out_kernel, dim3(Hz / 256, BLz / 128), dim3(512), 0, stream,
                       convb, WoutT, out);
}